// Round 3
// baseline (430.225 us; speedup 1.0000x reference)
//
#include <hip/hip_runtime.h>

// Sparsify1D: per-row top-K mask. rows=16384, cols=4096, K=3276 (keep top 80%).
// Exact per-row K-th-largest via 3-pass radix select (12+12+8 bits) on
// monotone sortable keys; row lives in registers (16 floats/thread).
// Row is read from HBM exactly once and written exactly once -> memory-bound.

static constexpr int COLS    = 4096;
static constexpr int K_RANK  = 3276;          // int(4096 * (1 - 0.2))
static constexpr int THREADS = 256;
static constexpr int EPT     = COLS / THREADS; // 16
static constexpr int NBINS   = 4096;           // 12-bit digit

__device__ __forceinline__ unsigned f2k(float f) {
    unsigned b = __float_as_uint(f);
    // positive: flip sign bit; negative: flip all bits -> unsigned order == float order
    return b ^ ((unsigned)((int)b >> 31) | 0x80000000u);
}

__global__ __launch_bounds__(THREADS)
void sparsify_topk_kernel(const float* __restrict__ x, float* __restrict__ out) {
    __shared__ unsigned hist[NBINS];
    __shared__ unsigned wavesum[4];
    __shared__ unsigned bc_digit;
    __shared__ unsigned bc_rank;

    const int t    = threadIdx.x;
    const int lane = t & 63;
    const int wave = t >> 6;
    const size_t rowbase = (size_t)blockIdx.x * COLS;

    // ---- load row: 4 coalesced float4 per thread ----
    float    val[EPT];
    unsigned key[EPT];
    const float4* xv = reinterpret_cast<const float4*>(x + rowbase);
#pragma unroll
    for (int c = 0; c < 4; ++c) {
        float4 v = xv[c * THREADS + t];
        val[c * 4 + 0] = v.x; val[c * 4 + 1] = v.y;
        val[c * 4 + 2] = v.z; val[c * 4 + 3] = v.w;
    }
#pragma unroll
    for (int e = 0; e < EPT; ++e) key[e] = f2k(val[e]);

    unsigned r = K_RANK;   // 1-indexed rank from the top
    unsigned prefix = 0;   // resolved high bits of the K-th largest key

    // ================= pass 0: bits 31..20 (4096 bins) =================
#pragma unroll
    for (int i = 0; i < NBINS / THREADS; ++i) hist[t + i * THREADS] = 0;
    __syncthreads();
#pragma unroll
    for (int e = 0; e < EPT; ++e) atomicAdd(&hist[key[e] >> 20], 1u);
    __syncthreads();
    {
        // thread t owns bins [t*16, t*16+16)
        unsigned s = 0;
#pragma unroll
        for (int i = 0; i < 16; ++i) s += hist[t * 16 + i];
        // wave-level inclusive SUFFIX scan (sum over lanes >= lane)
        unsigned S = s;
#pragma unroll
        for (int off = 1; off < 64; off <<= 1) {
            unsigned o = __shfl_down(S, off);
            S += (lane + off < 64) ? o : 0u;
        }
        if (lane == 0) wavesum[wave] = S;   // wave total
        __syncthreads();
        unsigned addhi = 0;
#pragma unroll
        for (int w = 0; w < 4; ++w) addhi += (w > wave) ? wavesum[w] : 0u;
        S += addhi;                          // S = sum over threads >= t
        if (S >= r && S - s < r) {           // unique crossing: S_t >= r > S_{t+1}
            unsigned cum = S - s;            // count strictly above my bins
            for (int d = 15; d >= 0; --d) {
                unsigned h = hist[t * 16 + d];
                if (cum + h >= r) { bc_digit = (unsigned)(t * 16 + d); bc_rank = r - cum; break; }
                cum += h;
            }
        }
        __syncthreads();                     // bc_* published; hist reads done
        prefix = bc_digit << 20;
        r = bc_rank;
    }

    // ================= pass 1: bits 19..8 (4096 bins) =================
#pragma unroll
    for (int i = 0; i < NBINS / THREADS; ++i) hist[t + i * THREADS] = 0;
    __syncthreads();
#pragma unroll
    for (int e = 0; e < EPT; ++e) {
        if ((key[e] >> 20) == (prefix >> 20))
            atomicAdd(&hist[(key[e] >> 8) & 0xFFFu], 1u);
    }
    __syncthreads();
    {
        unsigned s = 0;
#pragma unroll
        for (int i = 0; i < 16; ++i) s += hist[t * 16 + i];
        unsigned S = s;
#pragma unroll
        for (int off = 1; off < 64; off <<= 1) {
            unsigned o = __shfl_down(S, off);
            S += (lane + off < 64) ? o : 0u;
        }
        if (lane == 0) wavesum[wave] = S;
        __syncthreads();
        unsigned addhi = 0;
#pragma unroll
        for (int w = 0; w < 4; ++w) addhi += (w > wave) ? wavesum[w] : 0u;
        S += addhi;
        if (S >= r && S - s < r) {
            unsigned cum = S - s;
            for (int d = 15; d >= 0; --d) {
                unsigned h = hist[t * 16 + d];
                if (cum + h >= r) { bc_digit = (unsigned)(t * 16 + d); bc_rank = r - cum; break; }
                cum += h;
            }
        }
        __syncthreads();
        prefix |= bc_digit << 8;
        r = bc_rank;
    }

    // ================= pass 2: bits 7..0 (256 bins) =================
    hist[t] = 0;
    __syncthreads();
#pragma unroll
    for (int e = 0; e < EPT; ++e) {
        if ((key[e] >> 8) == (prefix >> 8))
            atomicAdd(&hist[key[e] & 0xFFu], 1u);
    }
    __syncthreads();
    {
        unsigned s = hist[t];   // thread t owns digit t
        unsigned S = s;
#pragma unroll
        for (int off = 1; off < 64; off <<= 1) {
            unsigned o = __shfl_down(S, off);
            S += (lane + off < 64) ? o : 0u;
        }
        if (lane == 0) wavesum[wave] = S;
        __syncthreads();
        unsigned addhi = 0;
#pragma unroll
        for (int w = 0; w < 4; ++w) addhi += (w > wave) ? wavesum[w] : 0u;
        S += addhi;
        if (S >= r && S - s < r) bc_digit = (unsigned)t;
        __syncthreads();
    }
    const unsigned kth = prefix | bc_digit;  // exact key of the K-th largest

    // ---- write: keep iff key >= kth (exact float order; ties match reference) ----
    float4* ov = reinterpret_cast<float4*>(out + rowbase);
#pragma unroll
    for (int c = 0; c < 4; ++c) {
        float4 v;
        v.x = (key[c * 4 + 0] >= kth) ? val[c * 4 + 0] : 0.0f;
        v.y = (key[c * 4 + 1] >= kth) ? val[c * 4 + 1] : 0.0f;
        v.z = (key[c * 4 + 2] >= kth) ? val[c * 4 + 2] : 0.0f;
        v.w = (key[c * 4 + 3] >= kth) ? val[c * 4 + 3] : 0.0f;
        ov[c * THREADS + t] = v;
    }
}

extern "C" void kernel_launch(void* const* d_in, const int* in_sizes, int n_in,
                              void* d_out, int out_size, void* d_ws, size_t ws_size,
                              hipStream_t stream) {
    const float* x = (const float*)d_in[0];
    float* out = (float*)d_out;
    const int rows = in_sizes[0] / COLS;
    sparsify_topk_kernel<<<rows, THREADS, 0, stream>>>(x, out);
}

// Round 6
// 418.834 us; speedup vs baseline: 1.0272x; 1.0272x over previous
//
#include <hip/hip_runtime.h>

// Sparsify1D: per-row top-K mask. rows=16384, cols=4096, K=3276 (keep top 80%).
// Exact per-row K-th-largest via 3-pass radix select (12+12+8 bits) on
// monotone sortable keys; row lives in registers (16 floats/thread).
// Row read from HBM exactly once, written exactly once -> memory-bound.
// Measured r3: kernel <166us (below harness fill dispatches); ~83% of 81us floor.
// r5 fix: __builtin_nontemporal_* needs clang ext_vector, not HIP float4 class.

static constexpr int COLS    = 4096;
static constexpr int K_RANK  = 3276;          // int(4096 * (1 - 0.2))
static constexpr int THREADS = 256;
static constexpr int EPT     = COLS / THREADS; // 16
static constexpr int NBINS   = 4096;           // 12-bit digit

typedef float  f32x4 __attribute__((ext_vector_type(4)));
typedef unsigned u32x4 __attribute__((ext_vector_type(4)));

__device__ __forceinline__ unsigned f2k(float f) {
    unsigned b = __float_as_uint(f);
    // positive: flip sign bit; negative: flip all bits -> unsigned order == float order
    return b ^ ((unsigned)((int)b >> 31) | 0x80000000u);
}

__global__ __launch_bounds__(THREADS, 4)
void sparsify_topk_kernel(const float* __restrict__ x, float* __restrict__ out) {
    __shared__ unsigned hist[NBINS];    // passes 0 and 1 (zeroed-in-scan between)
    __shared__ unsigned hist2[THREADS]; // pass 2, pre-zeroed at init
    __shared__ unsigned wavesum[4];
    __shared__ unsigned bc_digit;
    __shared__ unsigned bc_rank;

    const int t    = threadIdx.x;
    const int lane = t & 63;
    const int wave = t >> 6;
    const size_t rowbase = (size_t)blockIdx.x * COLS;

    // ---- issue row loads first (4 coalesced nontemporal 16B loads/thread),
    //      LDS init overlaps the HBM latency ----
    const f32x4* xv = reinterpret_cast<const f32x4*>(x + rowbase);
    f32x4 v0 = __builtin_nontemporal_load(&xv[0 * THREADS + t]);
    f32x4 v1 = __builtin_nontemporal_load(&xv[1 * THREADS + t]);
    f32x4 v2 = __builtin_nontemporal_load(&xv[2 * THREADS + t]);
    f32x4 v3 = __builtin_nontemporal_load(&xv[3 * THREADS + t]);

    u32x4* h4 = reinterpret_cast<u32x4*>(hist);
    const u32x4 zero4 = {0u, 0u, 0u, 0u};
#pragma unroll
    for (int i = 0; i < 4; ++i) h4[t + i * THREADS] = zero4;
    hist2[t] = 0u;
    __syncthreads();                                    // B1: hist zeroed

    float    val[EPT];
    unsigned key[EPT];
    val[0]=v0.x; val[1]=v0.y; val[2]=v0.z; val[3]=v0.w;
    val[4]=v1.x; val[5]=v1.y; val[6]=v1.z; val[7]=v1.w;
    val[8]=v2.x; val[9]=v2.y; val[10]=v2.z; val[11]=v2.w;
    val[12]=v3.x; val[13]=v3.y; val[14]=v3.z; val[15]=v3.w;
#pragma unroll
    for (int e = 0; e < EPT; ++e) key[e] = f2k(val[e]);

    unsigned r = K_RANK;   // 1-indexed rank from the top
    unsigned prefix = 0;   // resolved high bits of the K-th largest key

    // ================= pass 0: bits 31..20 (4096 bins) =================
#pragma unroll
    for (int e = 0; e < EPT; ++e) atomicAdd(&hist[key[e] >> 20], 1u);
    __syncthreads();                                    // B2: counts visible
    {
        // thread t owns bins [t*16, t*16+16); read into regs, then zero own
        // bins in-place (saves pass-1's zero+barrier pair).
        unsigned h[16];
#pragma unroll
        for (int i = 0; i < 4; ++i) {
            u32x4 q = h4[t * 4 + i];
            h[i*4+0]=q.x; h[i*4+1]=q.y; h[i*4+2]=q.z; h[i*4+3]=q.w;
        }
        unsigned s = 0;
#pragma unroll
        for (int i = 0; i < 16; ++i) s += h[i];
#pragma unroll
        for (int i = 0; i < 4; ++i) h4[t * 4 + i] = zero4;
        // wave-level inclusive SUFFIX scan (sum over lanes >= lane)
        unsigned S = s;
#pragma unroll
        for (int off = 1; off < 64; off <<= 1) {
            unsigned o = __shfl_down(S, off);
            S += (lane + off < 64) ? o : 0u;
        }
        if (lane == 0) wavesum[wave] = S;
        __syncthreads();                                // B3: wavesum + zeroing done
        unsigned addhi = 0;
#pragma unroll
        for (int w = 0; w < 4; ++w) addhi += (w > wave) ? wavesum[w] : 0u;
        S += addhi;                          // S = sum over threads >= t
        if (S >= r && S - s < r) {           // unique crossing: S_t >= r > S_{t+1}
            unsigned cum = S - s;            // count strictly above my bins
            bool done = false;
#pragma unroll
            for (int d = 15; d >= 0; --d) {  // compile-time indices -> h stays in regs
                unsigned hh = h[d];
                if (!done && cum + hh >= r) { bc_digit = (unsigned)(t * 16 + d); bc_rank = r - cum; done = true; }
                if (!done) cum += hh;
            }
        }
        __syncthreads();                                // B4: bc_* published
        prefix = bc_digit << 20;
        r = bc_rank;
    }

    // ================= pass 1: bits 19..8 (4096 bins, pre-zeroed) =================
#pragma unroll
    for (int e = 0; e < EPT; ++e) {
        if ((key[e] >> 20) == (prefix >> 20))
            atomicAdd(&hist[(key[e] >> 8) & 0xFFFu], 1u);
    }
    __syncthreads();                                    // B5
    {
        unsigned h[16];
#pragma unroll
        for (int i = 0; i < 4; ++i) {
            u32x4 q = h4[t * 4 + i];
            h[i*4+0]=q.x; h[i*4+1]=q.y; h[i*4+2]=q.z; h[i*4+3]=q.w;
        }
        unsigned s = 0;
#pragma unroll
        for (int i = 0; i < 16; ++i) s += h[i];
        unsigned S = s;
#pragma unroll
        for (int off = 1; off < 64; off <<= 1) {
            unsigned o = __shfl_down(S, off);
            S += (lane + off < 64) ? o : 0u;
        }
        if (lane == 0) wavesum[wave] = S;
        __syncthreads();                                // B6
        unsigned addhi = 0;
#pragma unroll
        for (int w = 0; w < 4; ++w) addhi += (w > wave) ? wavesum[w] : 0u;
        S += addhi;
        if (S >= r && S - s < r) {
            unsigned cum = S - s;
            bool done = false;
#pragma unroll
            for (int d = 15; d >= 0; --d) {
                unsigned hh = h[d];
                if (!done && cum + hh >= r) { bc_digit = (unsigned)(t * 16 + d); bc_rank = r - cum; done = true; }
                if (!done) cum += hh;
            }
        }
        __syncthreads();                                // B7: bc_* published
        prefix |= bc_digit << 8;
        r = bc_rank;
    }

    // ================= pass 2: bits 7..0 (256 bins, pre-zeroed hist2) =================
#pragma unroll
    for (int e = 0; e < EPT; ++e) {
        if ((key[e] >> 8) == (prefix >> 8))
            atomicAdd(&hist2[key[e] & 0xFFu], 1u);
    }
    __syncthreads();                                    // B8
    {
        unsigned s = hist2[t];   // thread t owns digit t
        unsigned S = s;
#pragma unroll
        for (int off = 1; off < 64; off <<= 1) {
            unsigned o = __shfl_down(S, off);
            S += (lane + off < 64) ? o : 0u;
        }
        if (lane == 0) wavesum[wave] = S;
        __syncthreads();                                // B9
        unsigned addhi = 0;
#pragma unroll
        for (int w = 0; w < 4; ++w) addhi += (w > wave) ? wavesum[w] : 0u;
        S += addhi;
        if (S >= r && S - s < r) bc_digit = (unsigned)t;
        __syncthreads();                                // B10: bc_digit published
    }
    const unsigned kth = prefix | bc_digit;  // exact key of the K-th largest

    // ---- write: keep iff key >= kth (exact float order; ties match reference) ----
    f32x4* ov = reinterpret_cast<f32x4*>(out + rowbase);
#pragma unroll
    for (int c = 0; c < 4; ++c) {
        f32x4 v;
        v.x = (key[c * 4 + 0] >= kth) ? val[c * 4 + 0] : 0.0f;
        v.y = (key[c * 4 + 1] >= kth) ? val[c * 4 + 1] : 0.0f;
        v.z = (key[c * 4 + 2] >= kth) ? val[c * 4 + 2] : 0.0f;
        v.w = (key[c * 4 + 3] >= kth) ? val[c * 4 + 3] : 0.0f;
        __builtin_nontemporal_store(v, &ov[c * THREADS + t]);
    }
}

extern "C" void kernel_launch(void* const* d_in, const int* in_sizes, int n_in,
                              void* d_out, int out_size, void* d_ws, size_t ws_size,
                              hipStream_t stream) {
    const float* x = (const float*)d_in[0];
    float* out = (float*)d_out;
    const int rows = in_sizes[0] / COLS;
    sparsify_topk_kernel<<<rows, THREADS, 0, stream>>>(x, out);
}